// Round 1
// baseline (846.789 us; speedup 1.0000x reference)
//
#include <hip/hip_runtime.h>
#include <hip/hip_bf16.h>

#define VOCAB 32000
#define EMB   128
#define HID   128
#define BB    8
#define SS    1024

typedef __bf16 bf16x8_t __attribute__((ext_vector_type(8)));
typedef float  f32x4_t  __attribute__((ext_vector_type(4)));

// ---------------------------------------------------------------------------
// Kernel A: xp[b,s,h] = sum_e emb[x[b,s],e] * W_ih[h,e] + b_ih[h] + b_hh[h]
// 256 blocks x 512 threads; thread = (h = t>>2, ks = t&3); W_ih row-slice in
// registers; e-row double-buffered in LDS (1 barrier per row).
// ---------------------------------------------------------------------------
__global__ __launch_bounds__(512) void xproj_kernel(
    const int* __restrict__ x, const float* __restrict__ emb,
    const float* __restrict__ W_ih, const float* __restrict__ b_ih,
    const float* __restrict__ b_hh, float* __restrict__ xp)
{
    const int t  = threadIdx.x;
    const int h  = t >> 2;
    const int ks = t & 3;

    float w[32];
    {
        const float* wr = W_ih + h * EMB + ks * 32;
        #pragma unroll
        for (int i = 0; i < 32; i += 4) {
            float4 v = *(const float4*)(wr + i);
            w[i] = v.x; w[i+1] = v.y; w[i+2] = v.z; w[i+3] = v.w;
        }
    }
    const float bias = b_ih[h] + b_hh[h];

    __shared__ float el[2][EMB];
    const int base = blockIdx.x * 32;

    float4 v = make_float4(0.f, 0.f, 0.f, 0.f);
    if (t < 32) v = *(const float4*)(emb + (size_t)x[base] * EMB + t * 4);

    for (int r = 0; r < 32; ++r) {
        if (t < 32) *(float4*)(&el[r & 1][t * 4]) = v;
        __syncthreads();
        if (t < 32 && r + 1 < 32)
            v = *(const float4*)(emb + (size_t)x[base + r + 1] * EMB + t * 4);

        float a0 = 0.f, a1 = 0.f, a2 = 0.f, a3 = 0.f;
        const float* e = &el[r & 1][ks * 32];
        #pragma unroll
        for (int c = 0; c < 8; ++c) {
            float4 hv = *(const float4*)(e + c * 4);
            a0 = fmaf(w[c*4+0], hv.x, a0);
            a1 = fmaf(w[c*4+1], hv.y, a1);
            a2 = fmaf(w[c*4+2], hv.z, a2);
            a3 = fmaf(w[c*4+3], hv.w, a3);
        }
        float sum = (a0 + a1) + (a2 + a3);
        sum += __shfl_xor(sum, 1);
        sum += __shfl_xor(sum, 2);
        if (ks == 0) xp[(size_t)(base + r) * HID + h] = bias + sum;
    }
}

// ---------------------------------------------------------------------------
// Kernel D: fp32 -> bf16 convert for fc_W (8 elems/thread, vectorized)
// ---------------------------------------------------------------------------
__global__ __launch_bounds__(256) void convert_bf16_kernel(
    const float* __restrict__ in, __hip_bfloat16* __restrict__ out)
{
    const size_t i = ((size_t)blockIdx.x * 256 + threadIdx.x) * 8;
    float4 a = *(const float4*)(in + i);
    float4 b = *(const float4*)(in + i + 4);
    union { __hip_bfloat16 h[8]; uint4 u; } p;
    p.h[0] = __float2bfloat16(a.x); p.h[1] = __float2bfloat16(a.y);
    p.h[2] = __float2bfloat16(a.z); p.h[3] = __float2bfloat16(a.w);
    p.h[4] = __float2bfloat16(b.x); p.h[5] = __float2bfloat16(b.y);
    p.h[6] = __float2bfloat16(b.z); p.h[7] = __float2bfloat16(b.w);
    *(uint4*)(out + i) = p.u;
}

// ---------------------------------------------------------------------------
// Kernel B: recurrence. 8 blocks (one per batch) x 512 threads.
// thread = (j = t>>2, ks = t&3) owns output j, K-slice ks. W_hh slice in
// registers; h double-buffered in LDS; ONE barrier per step.
// h_new = tanh(xp[t] + h @ W_hh^T); outputs written as bf16 for the FC GEMM;
// final h written fp32 to the hidden-state output.
// ---------------------------------------------------------------------------
__global__ __launch_bounds__(512) void rnn_kernel(
    const float* __restrict__ xp, const float* __restrict__ W_hh,
    __hip_bfloat16* __restrict__ hs_bf16, float* __restrict__ hidden_out)
{
    const int b  = blockIdx.x;
    const int t  = threadIdx.x;
    const int j  = t >> 2;
    const int ks = t & 3;

    float w[32];
    {
        const float* wr = W_hh + j * HID + ks * 32;
        #pragma unroll
        for (int i = 0; i < 32; i += 4) {
            float4 v = *(const float4*)(wr + i);
            w[i] = v.x; w[i+1] = v.y; w[i+2] = v.z; w[i+3] = v.w;
        }
    }

    __shared__ float hbuf[2][HID];
    if (t < HID) hbuf[0][t] = 0.f;

    const float* xpb = xp + (size_t)b * SS * HID;
    float xp0 = xpb[j];
    float xp1 = xpb[HID + j];
    __syncthreads();

    for (int step = 0; step < SS; ++step) {
        const float* hc = &hbuf[step & 1][ks * 32];
        float a0 = 0.f, a1 = 0.f, a2 = 0.f, a3 = 0.f;
        #pragma unroll
        for (int c = 0; c < 8; ++c) {
            float4 hv = *(const float4*)(hc + c * 4);
            a0 = fmaf(w[c*4+0], hv.x, a0);
            a1 = fmaf(w[c*4+1], hv.y, a1);
            a2 = fmaf(w[c*4+2], hv.z, a2);
            a3 = fmaf(w[c*4+3], hv.w, a3);
        }
        float sum = (a0 + a1) + (a2 + a3);
        sum += __shfl_xor(sum, 1);
        sum += __shfl_xor(sum, 2);

        const float xpt = xp0;
        xp0 = xp1;
        if (step + 2 < SS) xp1 = xpb[(size_t)(step + 2) * HID + j];

        if (ks == 0) {
            float hn = tanhf(xpt + sum);
            hbuf[(step + 1) & 1][j] = hn;
            hs_bf16[((size_t)b * SS + step) * HID + j] = __float2bfloat16(hn);
            if (step == SS - 1) hidden_out[b * HID + j] = hn;
        }
        __syncthreads();
    }
}

// ---------------------------------------------------------------------------
// Kernel C: logits[m, v] = sum_h A[m,h] * fcW[v,h] + fc_b[v]
// M=8192, N=32000, K=128. 128x128 tile per block, 4 waves of 64x64 each.
// MFMA 16x16x32 bf16; A and B fragments fed straight from L2/L3 (no LDS) —
// the kernel is HBM-write-bound so read latency hides under stores.
// ---------------------------------------------------------------------------
__global__ __launch_bounds__(256) void fc_kernel(
    const __hip_bfloat16* __restrict__ A, const __hip_bfloat16* __restrict__ Wb,
    const float* __restrict__ fc_b, float* __restrict__ C)
{
    const int lane = threadIdx.x & 63;
    const int wv   = threadIdx.x >> 6;
    const int wm   = wv >> 1;
    const int wn   = wv & 1;
    const int nb   = blockIdx.x % 250;
    const int mb   = blockIdx.x / 250;
    const int m0   = mb * 128 + wm * 64;
    const int n0   = nb * 128 + wn * 64;
    const int lr   = lane & 15;
    const int kq   = lane >> 4;

    f32x4_t acc[4][4];
    #pragma unroll
    for (int i = 0; i < 4; ++i)
        #pragma unroll
        for (int jj = 0; jj < 4; ++jj)
            acc[i][jj] = (f32x4_t){0.f, 0.f, 0.f, 0.f};

    #pragma unroll
    for (int kk = 0; kk < 4; ++kk) {
        const int ko = kk * 32 + kq * 8;
        bf16x8_t af[4], bfr[4];
        #pragma unroll
        for (int mt = 0; mt < 4; ++mt)
            af[mt] = *(const bf16x8_t*)(A + (size_t)(m0 + mt * 16 + lr) * HID + ko);
        #pragma unroll
        for (int nt = 0; nt < 4; ++nt)
            bfr[nt] = *(const bf16x8_t*)(Wb + (size_t)(n0 + nt * 16 + lr) * HID + ko);
        #pragma unroll
        for (int mt = 0; mt < 4; ++mt)
            #pragma unroll
            for (int nt = 0; nt < 4; ++nt)
                acc[mt][nt] = __builtin_amdgcn_mfma_f32_16x16x32_bf16(
                    af[mt], bfr[nt], acc[mt][nt], 0, 0, 0);
    }

    #pragma unroll
    for (int nt = 0; nt < 4; ++nt) {
        const int col = n0 + nt * 16 + lr;
        const float fcb = fc_b[col];
        #pragma unroll
        for (int mt = 0; mt < 4; ++mt) {
            const int row = m0 + mt * 16 + kq * 4;
            #pragma unroll
            for (int rr = 0; rr < 4; ++rr)
                C[(size_t)(row + rr) * VOCAB + col] = acc[mt][nt][rr] + fcb;
        }
    }
}

// ---------------------------------------------------------------------------
extern "C" void kernel_launch(void* const* d_in, const int* in_sizes, int n_in,
                              void* d_out, int out_size, void* d_ws, size_t ws_size,
                              hipStream_t stream)
{
    const int*   x    = (const int*)  d_in[0];
    const float* emb  = (const float*)d_in[1];
    const float* W_ih = (const float*)d_in[2];
    const float* b_ih = (const float*)d_in[3];
    const float* W_hh = (const float*)d_in[4];
    const float* b_hh = (const float*)d_in[5];
    const float* fc_W = (const float*)d_in[6];
    const float* fc_b = (const float*)d_in[7];

    float* logits = (float*)d_out;
    float* hidden = logits + (size_t)BB * SS * VOCAB;

    char* ws = (char*)d_ws;
    float*           xp  = (float*)ws;                               // 4,194,304 B
    __hip_bfloat16*  hsb = (__hip_bfloat16*)(ws + 4194304);          // 2,097,152 B
    __hip_bfloat16*  fwb = (__hip_bfloat16*)(ws + 6291456);          // 8,192,000 B

    xproj_kernel<<<dim3(256), dim3(512), 0, stream>>>(x, emb, W_ih, b_ih, b_hh, xp);
    convert_bf16_kernel<<<dim3(2000), dim3(256), 0, stream>>>(fc_W, fwb);
    rnn_kernel<<<dim3(8), dim3(512), 0, stream>>>(xp, W_hh, hsb, hidden);
    fc_kernel<<<dim3(16000), dim3(256), 0, stream>>>(hsb, fwb, fc_b, logits);
}